// Round 1
// 1179.127 us; speedup vs baseline: 1.0048x; 1.0048x over previous
//
#include <hip/hip_runtime.h>
#include <cmath>

#define DIM    2048
#define NHEADS 16
#define HD     128
#define HIDDEN 8192
#define SEQ    2048
#define MTOK   4096   // BATCH*SEQ
#define EPS    1e-6f

typedef __bf16 bf16;
typedef __bf16 bf16x8 __attribute__((ext_vector_type(8)));
typedef __bf16 bf16x4 __attribute__((ext_vector_type(4)));
typedef float  f32x4  __attribute__((ext_vector_type(4)));

typedef __attribute__((address_space(1))) const void gvoid_t;
typedef __attribute__((address_space(3))) void lvoid_t;

// ------- batched transpose + fp32->bf16 convert: out[c][r] = in[r][c], z picks matrix ----
__global__ void k_transpose4(const float* __restrict__ in0, const float* __restrict__ in1,
                             const float* __restrict__ in2, const float* __restrict__ in3,
                             bf16* __restrict__ o0, bf16* __restrict__ o1,
                             bf16* __restrict__ o2, bf16* __restrict__ o3,
                             int R, int C) {
    __shared__ float tile[64][65];
    const float* in = blockIdx.z == 0 ? in0 : blockIdx.z == 1 ? in1 : blockIdx.z == 2 ? in2 : in3;
    bf16* out       = blockIdx.z == 0 ? o0  : blockIdx.z == 1 ? o1  : blockIdx.z == 2 ? o2  : o3;
    int r0 = blockIdx.y * 64, c0 = blockIdx.x * 64;
    int tx = threadIdx.x, ty = threadIdx.y;
#pragma unroll
    for (int i = ty; i < 64; i += 4)
        tile[i][tx] = in[(size_t)(r0 + i) * C + (c0 + tx)];
    __syncthreads();
#pragma unroll
    for (int i = ty; i < 64; i += 4)
        out[(size_t)(c0 + i) * R + (r0 + tx)] = (bf16)tile[tx][i];
}

// ---------------- RMSNorm: fp32 in -> bf16 out ----------------
__global__ void k_rmsnorm(const float* __restrict__ x, const float* __restrict__ w,
                          bf16* __restrict__ out) {
    int row = blockIdx.x;
    int tid = threadIdx.x;
    const float4* xr = (const float4*)(x + (size_t)row * DIM);
    float4 a = xr[tid];
    float4 b = xr[tid + 256];
    float ss = a.x*a.x + a.y*a.y + a.z*a.z + a.w*a.w
             + b.x*b.x + b.y*b.y + b.z*b.z + b.w*b.w;
#pragma unroll
    for (int off = 32; off > 0; off >>= 1) ss += __shfl_down(ss, off, 64);
    __shared__ float red[4];
    if ((tid & 63) == 0) red[tid >> 6] = ss;
    __syncthreads();
    float tot = red[0] + red[1] + red[2] + red[3];
    float inv = rsqrtf(tot * (1.0f / DIM) + EPS);
    const float4* wr = (const float4*)w;
    float4 w0 = wr[tid], w1 = wr[tid + 256];
    bf16x4* o = (bf16x4*)(out + (size_t)row * DIM);
    bf16x4 v0, v1;
    v0[0] = (bf16)(a.x * inv * w0.x); v0[1] = (bf16)(a.y * inv * w0.y);
    v0[2] = (bf16)(a.z * inv * w0.z); v0[3] = (bf16)(a.w * inv * w0.w);
    v1[0] = (bf16)(b.x * inv * w1.x); v1[1] = (bf16)(b.y * inv * w1.y);
    v1[2] = (bf16)(b.z * inv * w1.z); v1[3] = (bf16)(b.w * inv * w1.w);
    o[tid] = v0;
    o[tid + 256] = v1;
}

// ---------------- legacy 128x128 GEMM (kept for MODE 2: fp32 out + residual) -------
template<int MODE>
__global__ __launch_bounds__(256, 2) void k_gemm(
    const bf16* __restrict__ A, const bf16* __restrict__ B1, const bf16* __restrict__ B2,
    const float* __restrict__ resid, const float* __restrict__ fcos,
    const float* __restrict__ fsin,
    bf16* __restrict__ oq, bf16* __restrict__ ok, bf16* __restrict__ ov,
    float* __restrict__ of, int M, int N, int K)
{
    __shared__ bf16 As [128][72];
    __shared__ bf16 Bs1[128][72];

    const int tid  = threadIdx.x;
    const int wid  = tid >> 6;
    const int lane = tid & 63;
    const int quad = lane >> 4;
    const int l16  = lane & 15;
    const int wm   = wid >> 1;
    const int wn   = wid & 1;
    const int m0   = blockIdx.y * 128;
    const int n0   = blockIdx.x * 128;
    const int tr   = tid >> 3;         // 0..31
    const int tc   = (tid & 7) * 8;    // 0..56

    f32x4 acc1[4][4] = {};

    const int nk = K >> 6;
    for (int kt = 0; kt < nk; ++kt) {
        const int k0 = kt << 6;
        __syncthreads();
#pragma unroll
        for (int p = 0; p < 4; ++p) {
            int row = p * 32 + tr;
            *(uint4*)&As [row][tc] = *(const uint4*)&A [(size_t)(m0 + row) * K + k0 + tc];
            *(uint4*)&Bs1[row][tc] = *(const uint4*)&B1[(size_t)(n0 + row) * K + k0 + tc];
        }
        __syncthreads();
#pragma unroll
        for (int kk = 0; kk < 64; kk += 32) {
            bf16x8 af[4], bf1[4];
#pragma unroll
            for (int i = 0; i < 4; ++i) {
                af[i]  = *(const bf16x8*)&As [wm * 64 + i * 16 + l16][kk + quad * 8];
                bf1[i] = *(const bf16x8*)&Bs1[wn * 64 + i * 16 + l16][kk + quad * 8];
            }
#pragma unroll
            for (int mi = 0; mi < 4; ++mi)
#pragma unroll
                for (int ni = 0; ni < 4; ++ni)
                    acc1[mi][ni] = __builtin_amdgcn_mfma_f32_16x16x32_bf16(
                        af[mi], bf1[ni], acc1[mi][ni], 0, 0, 0);
        }
    }

#pragma unroll
    for (int mi = 0; mi < 4; ++mi)
#pragma unroll
        for (int i = 0; i < 4; ++i) {
            int row = m0 + wm * 64 + mi * 16 + quad * 4 + i;
#pragma unroll
            for (int ni = 0; ni < 4; ++ni) {
                int col = n0 + wn * 64 + ni * 16 + l16;
                float v1 = acc1[mi][ni][i];
                of[(size_t)row * N + col] = resid[(size_t)row * N + col] + v1;
            }
        }
}

// =====================================================================================
// 8-phase 256-row double-buffered MFMA GEMM (plain-HIP port of the HK cdna4 schedule).
// LDS: 2 slots x 4 half-tiles (16KB each, [128 rows][64 k], XOR-swizzled 16B slots).
// Per phase: {ds_read next-quadrant frags | global_load_lds 1 half-tile | s_barrier |
//             lgkmcnt(0) | setprio(1) + 16 MFMA + setprio(0) | s_barrier}.
// One counted vmcnt(4) gate per K-tile (vmcnt(0) only at the tail).
// CFG 0: BM=256,BN=256, 2x4 waves, single B   (MODE 1: fused QKV + RoPE epilogue)
// CFG 1: BM=256,BN=128, 4x2 waves, dual B     (MODE 3: silu(A@B1^T) * (A@B2^T))
// =====================================================================================
template<int CFG, int MODE>
__global__ __launch_bounds__(512, 2) void k_gemm8p(
    const bf16* __restrict__ A, const bf16* __restrict__ B1,
    const bf16* __restrict__ B2,
    const float* __restrict__ fcos, const float* __restrict__ fsin,
    bf16* __restrict__ oq, bf16* __restrict__ ok, bf16* __restrict__ ov,
    int M, int N, int K)
{
    constexpr int BN  = CFG ? 128 : 256;
    constexpr int WN  = CFG ? 2 : 4;       // waves along N
    constexpr int WM  = 8 / WN;            // waves along M
    constexpr int MFR = (256 / WM) / 16;   // m-fragments per wave (8 or 4)
    constexpr int NLO = CFG ? 4 : 2;       // n-frags per b_lo / b_hi set

    __shared__ __align__(16) char lds[131072];

    const int tid  = threadIdx.x;
    const int wid  = tid >> 6;
    const int lane = tid & 63;
    const int quad = lane >> 4;
    const int l16  = lane & 15;
    const int wm   = wid / WN;
    const int wn   = wid % WN;
    const int m0   = blockIdx.y * 256;
    const int n0   = blockIdx.x * BN;
    const int NT   = K >> 6;
    (void)M;

    // swizzled 16B-slot offsets for ds_read; row%8 == l16%8 for all fragment rows
    const uint32_t swz0 = (uint32_t)(((0 + quad) ^ (l16 & 7)) << 4);
    const uint32_t swz1 = (uint32_t)(((4 + quad) ^ (l16 & 7)) << 4);
    const uint32_t a_base = (uint32_t)((wm * (256 / WM) + l16) * 128);
    const uint32_t b_base = (uint32_t)(32768 + (wn * 64 + l16) * 128);

    // stage one 16KB half-tile [128 rows][64 k] of K-tile Tt into LDS.
    // H: 0 = A rows 0-127, 1 = A rows 128-255, 2 = B(1) half0, 3 = B(2) half1.
    // global_load_lds writes linearly (wave base + lane*16); source col-slot is
    // pre-swizzled so the ds_read side applies the same XOR (involution).
    auto stage = [&](int H, int Tt) {
        const uint32_t lb = (uint32_t)(Tt & 1) * 65536u + (uint32_t)H * 16384u
                          + (uint32_t)wid * 1024u;
        const int k0 = Tt << 6;
        const bf16* gb; int grow;
        if (H < 2) { gb = A; grow = m0 + H * 128; }
        else if constexpr (CFG == 0) { gb = B1; grow = n0 + (H - 2) * 128; }
        else { gb = (H == 2) ? B1 : B2; grow = n0; }
#pragma unroll
        for (int rho = 0; rho < 2; ++rho) {
            const int r  = (tid >> 3) + rho * 64;
            const int sp = (tid & 7) ^ (r & 7);
            const bf16* g = gb + (size_t)(grow + r) * K + k0 + sp * 8;
            __builtin_amdgcn_global_load_lds((gvoid_t*)g,
                (lvoid_t*)&lds[lb + (uint32_t)rho * 8192u], 16, 0, 0);
        }
    };

    bf16x8 a_lo[MFR / 2][2], a_hi[MFR / 2][2];
    bf16x8 b_lo[NLO][2],     b_hi[NLO][2];
    f32x4  acc1[MFR][4] = {};
    f32x4  acc2[CFG ? 4 : 1][4] = {};

    auto rdA = [&](bf16x8 (&dst)[MFR / 2][2], int mbase, uint32_t sb) {
#pragma unroll
        for (int mi = 0; mi < MFR / 2; ++mi)
#pragma unroll
            for (int ks = 0; ks < 2; ++ks)
                dst[mi][ks] = *(const bf16x8*)&lds[sb + a_base
                    + (uint32_t)(mbase + mi) * 2048u + (ks ? swz1 : swz0)];
    };
    auto rdB = [&](bf16x8 (&dst)[NLO][2], int sel /*0=lo,1=hi*/, uint32_t sb) {
#pragma unroll
        for (int ni = 0; ni < NLO; ++ni)
#pragma unroll
            for (int ks = 0; ks < 2; ++ks) {
                uint32_t off;
                if constexpr (CFG == 0)
                    off = b_base + (uint32_t)(sel * 2 + ni) * 2048u;
                else
                    off = b_base + (uint32_t)sel * 16384u + (uint32_t)ni * 2048u;
                dst[ni][ks] = *(const bf16x8*)&lds[sb + off + (ks ? swz1 : swz0)];
            }
    };

    // ---------------- prologue: tile0 full + tile1 {B0,B1,A0}; A1(1) comes in-loop ---
    stage(0, 0); stage(1, 0); stage(2, 0); stage(3, 0);
    stage(2, 1); stage(3, 1); stage(0, 1);
    asm volatile("s_waitcnt vmcnt(6)" ::: "memory");   // tile0's 8 loads landed
    __builtin_amdgcn_s_barrier();
    rdA(a_lo, 0, 0u);
    rdB(b_lo, 0, 0u);

    for (int T = 0; T < NT; ++T) {
        const uint32_t sb  = (uint32_t)(T & 1) * 65536u;
        const uint32_t nsb = sb ^ 65536u;
        const bool st1 = (T + 1 < NT);
        const bool st2 = (T + 2 < NT);

        // ---- phase 0: read b_hi(T) | stage A_h1(T+1) | MFMA Q0 = a_lo x b_lo ----
        rdB(b_hi, 1, sb);
        if (st1) stage(1, T + 1);
        __builtin_amdgcn_s_barrier();
        asm volatile("s_waitcnt lgkmcnt(0)" ::: "memory");
        __builtin_amdgcn_s_setprio(1);
        if constexpr (CFG == 0) {
#pragma unroll
            for (int ks = 0; ks < 2; ++ks)
#pragma unroll
                for (int mi = 0; mi < 4; ++mi)
#pragma unroll
                    for (int ni = 0; ni < 2; ++ni)
                        acc1[mi][ni] = __builtin_amdgcn_mfma_f32_16x16x32_bf16(
                            a_lo[mi][ks], b_lo[ni][ks], acc1[mi][ni], 0, 0, 0);
        } else {
#pragma unroll
            for (int ks = 0; ks < 2; ++ks)
#pragma unroll
                for (int mi = 0; mi < 2; ++mi)
#pragma unroll
                    for (int ni = 0; ni < 4; ++ni)
                        acc1[mi][ni] = __builtin_amdgcn_mfma_f32_16x16x32_bf16(
                            a_lo[mi][ks], b_lo[ni][ks], acc1[mi][ni], 0, 0, 0);
        }
        __builtin_amdgcn_s_setprio(0);
        __builtin_amdgcn_s_barrier();

        // ---- phase 1: read a_hi(T) | stage B_h0(T+2) | MFMA Q1 = a_lo x b_hi ----
        rdA(a_hi, MFR / 2, sb);
        if (st2) stage(2, T + 2);
        __builtin_amdgcn_s_barrier();
        asm volatile("s_waitcnt lgkmcnt(0)" ::: "memory");
        __builtin_amdgcn_s_setprio(1);
        if constexpr (CFG == 0) {
#pragma unroll
            for (int ks = 0; ks < 2; ++ks)
#pragma unroll
                for (int mi = 0; mi < 4; ++mi)
#pragma unroll
                    for (int ni = 0; ni < 2; ++ni)
                        acc1[mi][2 + ni] = __builtin_amdgcn_mfma_f32_16x16x32_bf16(
                            a_lo[mi][ks], b_hi[ni][ks], acc1[mi][2 + ni], 0, 0, 0);
        } else {
#pragma unroll
            for (int ks = 0; ks < 2; ++ks)
#pragma unroll
                for (int mi = 0; mi < 2; ++mi)
#pragma unroll
                    for (int ni = 0; ni < 4; ++ni)
                        acc2[mi][ni] = __builtin_amdgcn_mfma_f32_16x16x32_bf16(
                            a_lo[mi][ks], b_hi[ni][ks], acc2[mi][ni], 0, 0, 0);
        }
        __builtin_amdgcn_s_setprio(0);
        __builtin_amdgcn_s_barrier();

        // ---- phase 2: stage B_h1(T+2) | MFMA Q2 = a_hi x b_lo | counted vmcnt gate --
        if (st2) stage(3, T + 2);
        __builtin_amdgcn_s_barrier();
        asm volatile("s_waitcnt lgkmcnt(0)" ::: "memory");
        __builtin_amdgcn_s_setprio(1);
        if constexpr (CFG == 0) {
#pragma unroll
            for (int ks = 0; ks < 2; ++ks)
#pragma unroll
                for (int mi = 0; mi < 4; ++mi)
#pragma unroll
                    for (int ni = 0; ni < 2; ++ni)
                        acc1[4 + mi][ni] = __builtin_amdgcn_mfma_f32_16x16x32_bf16(
                            a_hi[mi][ks], b_lo[ni][ks], acc1[4 + mi][ni], 0, 0, 0);
        } else {
#pragma unroll
            for (int ks = 0; ks < 2; ++ks)
#pragma unroll
                for (int mi = 0; mi < 2; ++mi)
#pragma unroll
                    for (int ni = 0; ni < 4; ++ni)
                        acc1[2 + mi][ni] = __builtin_amdgcn_mfma_f32_16x16x32_bf16(
                            a_hi[mi][ks], b_lo[ni][ks], acc1[2 + mi][ni], 0, 0, 0);
        }
        __builtin_amdgcn_s_setprio(0);
        if (st1) {   // gate: everything needed by phase 3's pre-read of T+1 has landed
            if (st2) asm volatile("s_waitcnt vmcnt(4)" ::: "memory");
            else     asm volatile("s_waitcnt vmcnt(0)" ::: "memory");
        }
        __builtin_amdgcn_s_barrier();

        // ---- phase 3: pre-read T+1 (a_lo,b_lo) | stage A_h0(T+2) | MFMA Q3 ----
        if (st1) { rdA(a_lo, 0, nsb); rdB(b_lo, 0, nsb); }
        if (st2) stage(0, T + 2);
        __builtin_amdgcn_s_barrier();
        asm volatile("s_waitcnt lgkmcnt(0)" ::: "memory");
        __builtin_amdgcn_s_setprio(1);
        if constexpr (CFG == 0) {
#pragma unroll
            for (int ks = 0; ks < 2; ++ks)
#pragma unroll
                for (int mi = 0; mi < 4; ++mi)
#pragma unroll
                    for (int ni = 0; ni < 2; ++ni)
                        acc1[4 + mi][2 + ni] = __builtin_amdgcn_mfma_f32_16x16x32_bf16(
                            a_hi[mi][ks], b_hi[ni][ks], acc1[4 + mi][2 + ni], 0, 0, 0);
        } else {
#pragma unroll
            for (int ks = 0; ks < 2; ++ks)
#pragma unroll
                for (int mi = 0; mi < 2; ++mi)
#pragma unroll
                    for (int ni = 0; ni < 4; ++ni)
                        acc2[2 + mi][ni] = __builtin_amdgcn_mfma_f32_16x16x32_bf16(
                            a_hi[mi][ks], b_hi[ni][ks], acc2[2 + mi][ni], 0, 0, 0);
        }
        __builtin_amdgcn_s_setprio(0);
        __builtin_amdgcn_s_barrier();
    }

    // -------- epilogue --------
    if constexpr (MODE == 1) {
        // block's BN=256 cols live in exactly one of q/k/v (2048 each)
        const int region = n0 >> 11;
        bf16* dst = region == 0 ? oq : (region == 1 ? ok : ov);
        const int c0 = (n0 & 2047) + wn * 64;
#pragma unroll
        for (int mi = 0; mi < MFR; ++mi)
#pragma unroll
            for (int i = 0; i < 4; ++i) {
                int row = m0 + wm * 128 + mi * 16 + quad * 4 + i;
                int pos = row & (SEQ - 1);
#pragma unroll
                for (int ni = 0; ni < 4; ++ni) {
                    int c = c0 + ni * 16 + l16;
                    float vA = acc1[mi][ni][i];
                    if (region < 2) {   // RoPE on q,k
                        float vB = __shfl_xor(vA, 1, 64);
                        int fi = (c & 127) >> 1;
                        float cs = fcos[pos * 64 + fi], sn = fsin[pos * 64 + fi];
                        vA = (l16 & 1) ? (vB * sn + vA * cs) : (vA * cs - vB * sn);
                    }
                    dst[(size_t)row * DIM + c] = (bf16)vA;
                }
            }
    } else {   // MODE 3: silu(A@B1^T) * (A@B2^T), bf16 out
#pragma unroll
        for (int mi = 0; mi < MFR; ++mi)
#pragma unroll
            for (int i = 0; i < 4; ++i) {
                int row = m0 + wm * 64 + mi * 16 + quad * 4 + i;
#pragma unroll
                for (int ni = 0; ni < 4; ++ni) {
                    int col = n0 + wn * 64 + ni * 16 + l16;
                    float v1 = acc1[mi][ni][i];
                    float v2 = acc2[mi][ni][i];
                    float g = v1 / (1.0f + __expf(-v1));
                    oq[(size_t)row * (size_t)N + col] = (bf16)(g * v2);
                }
            }
    }
}

// ---------------- Flash attention (causal), per (qtile, batch*head) -----------------
__global__ __launch_bounds__(256, 2) void k_flash(
    const bf16* __restrict__ q, const bf16* __restrict__ k,
    const bf16* __restrict__ v, bf16* __restrict__ o)
{
    const int qt = 15 - blockIdx.x;    // longest blocks first
    const int bh = blockIdx.y;
    const int b  = bh >> 4, h = bh & 15;
    const int tid  = threadIdx.x;
    const int wid  = tid >> 6, lane = tid & 63;
    const int quad = lane >> 4, l16 = lane & 15;

    __shared__ bf16 Ks [128][136];   // K tile [key][d]; reused as P tile [q][key]
    __shared__ bf16 Vts[128][136];   // V^T tile [d][key]

    const int q0 = qt * 128;
    const size_t baseQ  = ((size_t)b * SEQ + q0) * DIM + (size_t)h * HD;
    const size_t baseKV = ((size_t)b * SEQ) * DIM + (size_t)h * HD;

    bf16x8 qf[2][4];
#pragma unroll
    for (int mi = 0; mi < 2; ++mi)
#pragma unroll
        for (int ks = 0; ks < 4; ++ks)
            qf[mi][ks] = *(const bf16x8*)&q[baseQ +
                (size_t)(wid * 32 + mi * 16 + l16) * DIM + ks * 32 + quad * 8];

    f32x4 acc_o[2][8] = {};
    float m_run[2][4], l_run[2][4];
#pragma unroll
    for (int mi = 0; mi < 2; ++mi)
#pragma unroll
        for (int i = 0; i < 4; ++i) { m_run[mi][i] = -INFINITY; l_run[mi][i] = 0.f; }

    const float scale = 0.08838834764831845f;   // 1/sqrt(128)
    const int krow = tid >> 1, kcol = (tid & 1) * 64;

    for (int kt = 0; kt <= qt; ++kt) {
        const int kbase = kt * 128;
        __syncthreads();
#pragma unroll
        for (int j = 0; j < 8; ++j)
            *(uint4*)&Ks[krow][kcol + j * 8] =
                *(const uint4*)&k[baseKV + (size_t)(kbase + krow) * DIM + kcol + j * 8];
#pragma unroll
        for (int j = 0; j < 8; ++j) {
            bf16x8 vv = *(const bf16x8*)&v[baseKV + (size_t)(kbase + krow) * DIM + kcol + j * 8];
#pragma unroll
            for (int e = 0; e < 8; ++e)
                Vts[kcol + j * 8 + e][krow] = vv[e];
        }
        __syncthreads();

        f32x4 accs[2][8] = {};
#pragma unroll
        for (int ks = 0; ks < 4; ++ks)
#pragma unroll
            for (int ni = 0; ni < 8; ++ni) {
                bf16x8 kf = *(const bf16x8*)&Ks[ni * 16 + l16][ks * 32 + quad * 8];
#pragma unroll
                for (int mi = 0; mi < 2; ++mi)
                    accs[mi][ni] = __builtin_amdgcn_mfma_f32_16x16x32_bf16(
                        qf[mi][ks], kf, accs[mi][ni], 0, 0, 0);
            }

#pragma unroll
        for (int mi = 0; mi < 2; ++mi)
#pragma unroll
            for (int i = 0; i < 4; ++i) {
                int grow = q0 + wid * 32 + mi * 16 + quad * 4 + i;
                float mx = -INFINITY;
#pragma unroll
                for (int ni = 0; ni < 8; ++ni) {
                    float sv = accs[mi][ni][i] * scale;
                    int col = kbase + ni * 16 + l16;
                    if (col > grow) sv = -INFINITY;
                    accs[mi][ni][i] = sv;
                    mx = fmaxf(mx, sv);
                }
                mx = fmaxf(mx, __shfl_xor(mx, 1, 64));
                mx = fmaxf(mx, __shfl_xor(mx, 2, 64));
                mx = fmaxf(mx, __shfl_xor(mx, 4, 64));
                mx = fmaxf(mx, __shfl_xor(mx, 8, 64));
                float mnew  = fmaxf(m_run[mi][i], mx);
                float alpha = __expf(m_run[mi][i] - mnew);
                m_run[mi][i] = mnew;
                float rsum = 0.f;
#pragma unroll
                for (int ni = 0; ni < 8; ++ni) {
                    float p = __expf(accs[mi][ni][i] - mnew);
                    accs[mi][ni][i] = p;
                    rsum += p;
                }
                rsum += __shfl_xor(rsum, 1, 64);
                rsum += __shfl_xor(rsum, 2, 64);
                rsum += __shfl_xor(rsum, 4, 64);
                rsum += __shfl_xor(rsum, 8, 64);
                l_run[mi][i] = l_run[mi][i] * alpha + rsum;
#pragma unroll
                for (int ni = 0; ni < 8; ++ni) acc_o[mi][ni][i] *= alpha;
            }

        __syncthreads();
#pragma unroll
        for (int mi = 0; mi < 2; ++mi)
#pragma unroll
            for (int ni = 0; ni < 8; ++ni)
#pragma unroll
                for (int i = 0; i < 4; ++i)
                    Ks[wid * 32 + mi * 16 + quad * 4 + i][ni * 16 + l16] =
                        (bf16)accs[mi][ni][i];
        __syncthreads();

#pragma unroll
        for (int ks2 = 0; ks2 < 4; ++ks2) {
            bf16x8 pf[2];
#pragma unroll
            for (int mi = 0; mi < 2; ++mi)
                pf[mi] = *(const bf16x8*)&Ks[wid * 32 + mi * 16 + l16][ks2 * 32 + quad * 8];
#pragma unroll
            for (int ni = 0; ni < 8; ++ni) {
                bf16x8 vf = *(const bf16x8*)&Vts[ni * 16 + l16][ks2 * 32 + quad * 8];
#pragma unroll
                for (int mi = 0; mi < 2; ++mi)
                    acc_o[mi][ni] = __builtin_amdgcn_mfma_f32_16x16x32_bf16(
                        pf[mi], vf, acc_o[mi][ni], 0, 0, 0);
            }
        }
    }

#pragma unroll
    for (int mi = 0; mi < 2; ++mi)
#pragma unroll
        for (int i = 0; i < 4; ++i) {
            float invl = 1.0f / l_run[mi][i];
            int row = q0 + wid * 32 + mi * 16 + quad * 4 + i;
            size_t rb = ((size_t)b * SEQ + row) * DIM + (size_t)h * HD;
#pragma unroll
            for (int ni = 0; ni < 8; ++ni)
                o[rb + ni * 16 + l16] = (bf16)(acc_o[mi][ni][i] * invl);
        }
}

// ------------------------------- host launcher ---------------------------------------
extern "C" void kernel_launch(void* const* d_in, const int* in_sizes, int n_in,
                              void* d_out, int out_size, void* d_ws, size_t ws_size,
                              hipStream_t stream)
{
    (void)in_sizes; (void)n_in; (void)out_size; (void)ws_size;
    const float* x    = (const float*)d_in[0];
    const float* fcos = (const float*)d_in[1];
    const float* fsin = (const float*)d_in[2];
    const float* wq   = (const float*)d_in[4];
    const float* wk   = (const float*)d_in[5];
    const float* wv   = (const float*)d_in[6];
    const float* wo   = (const float*)d_in[7];
    const float* w1   = (const float*)d_in[8];
    const float* w2   = (const float*)d_in[9];
    const float* w3   = (const float*)d_in[10];
    const float* anw  = (const float*)d_in[11];
    const float* fnw  = (const float*)d_in[12];
    float* out = (float*)d_out;

    char* ws = (char*)d_ws;
    size_t off = 0;
    auto alloc = [&](size_t bytes) { void* p = ws + off; off += (bytes + 255) & ~255ull; return p; };
    bf16* wqT = (bf16*)alloc((size_t)DIM * DIM * 2);    // wq/wk/wv contiguous -> one B matrix
    bf16* wkT = (bf16*)alloc((size_t)DIM * DIM * 2);
    bf16* wvT = (bf16*)alloc((size_t)DIM * DIM * 2);
    bf16* woT = (bf16*)alloc((size_t)DIM * DIM * 2);
    bf16* w1T = (bf16*)alloc((size_t)HIDDEN * DIM * 2);
    bf16* w3T = (bf16*)alloc((size_t)HIDDEN * DIM * 2);
    bf16* xn  = (bf16*)alloc((size_t)MTOK * DIM * 2);   // also hn
    bf16* qb  = (bf16*)alloc((size_t)MTOK * DIM * 2);   // also attn out
    bf16* kb  = (bf16*)alloc((size_t)MTOK * DIM * 2);
    bf16* vb  = (bf16*)alloc((size_t)MTOK * DIM * 2);
    bf16* ffb = (bf16*)alloc((size_t)MTOK * HIDDEN * 2);
    bf16* w2T = kb;   // w2T [DIM][HIDDEN] reuses k+v region after attention

    dim3 tb(64, 4);
    // all four DIM x DIM weight transposes in ONE dispatch
    k_transpose4<<<dim3(DIM / 64, DIM / 64, 4), tb, 0, stream>>>(
        wq, wk, wv, wo, wqT, wkT, wvT, woT, DIM, DIM);
    // w1 + w3 in one dispatch
    k_transpose4<<<dim3(HIDDEN / 64, DIM / 64, 2), tb, 0, stream>>>(
        w1, w3, nullptr, nullptr, w1T, w3T, nullptr, nullptr, DIM, HIDDEN);

    k_rmsnorm<<<MTOK, 256, 0, stream>>>(x, anw, xn);

    // fused QKV projection + RoPE (B = [wqT|wkT|wvT] contiguous, N=6144), 8-phase
    k_gemm8p<0, 1><<<dim3(3 * DIM / 256, MTOK / 256), 512, 0, stream>>>(
        xn, wqT, nullptr, fcos, fsin, qb, kb, vb, MTOK, 3 * DIM, DIM);

    // attention -> writes into qb
    k_flash<<<dim3(SEQ / 128, 2 * NHEADS), 256, 0, stream>>>(qb, kb, vb, qb);

    // w2 transpose into dead k/v region (after flash; aliases kb)
    k_transpose4<<<dim3(DIM / 64, HIDDEN / 64, 1), tb, 0, stream>>>(
        w2, nullptr, nullptr, nullptr, w2T, nullptr, nullptr, nullptr, HIDDEN, DIM);

    // h = x + attn @ wo   (fp32, into d_out)
    k_gemm<2><<<dim3(DIM / 128, MTOK / 128), 256, 0, stream>>>(
        qb, woT, nullptr, x, nullptr, nullptr, nullptr, nullptr, nullptr, out, MTOK, DIM, DIM);

    k_rmsnorm<<<MTOK, 256, 0, stream>>>(out, fnw, xn);

    // ff = silu(hn@w1) * (hn@w3)  -- dual-B 8-phase, BN=128
    k_gemm8p<1, 3><<<dim3(HIDDEN / 128, MTOK / 256), 512, 0, stream>>>(
        xn, w1T, w3T, nullptr, nullptr, ffb, nullptr, nullptr, MTOK, HIDDEN, DIM);

    // out = h + ff @ w2
    k_gemm<2><<<dim3(DIM / 128, MTOK / 128), 256, 0, stream>>>(
        ffb, w2T, nullptr, out, nullptr, nullptr, nullptr, nullptr, nullptr, out,
        MTOK, DIM, HIDDEN);
}

// Round 2
// 1080.404 us; speedup vs baseline: 1.0967x; 1.0914x over previous
//
#include <hip/hip_runtime.h>
#include <cmath>

#define DIM    2048
#define NHEADS 16
#define HD     128
#define HIDDEN 8192
#define SEQ    2048
#define MTOK   4096   // BATCH*SEQ
#define EPS    1e-6f

typedef __bf16 bf16;
typedef __bf16 bf16x8 __attribute__((ext_vector_type(8)));
typedef __bf16 bf16x4 __attribute__((ext_vector_type(4)));
typedef float  f32x4  __attribute__((ext_vector_type(4)));

typedef __attribute__((address_space(1))) const void gvoid_t;
typedef __attribute__((address_space(3))) void lvoid_t;

// ------- batched transpose + fp32->bf16 convert: out[c][r] = in[r][c], z picks matrix ----
__global__ void k_transpose4(const float* __restrict__ in0, const float* __restrict__ in1,
                             const float* __restrict__ in2, const float* __restrict__ in3,
                             bf16* __restrict__ o0, bf16* __restrict__ o1,
                             bf16* __restrict__ o2, bf16* __restrict__ o3,
                             int R, int C) {
    __shared__ float tile[64][65];
    const float* in = blockIdx.z == 0 ? in0 : blockIdx.z == 1 ? in1 : blockIdx.z == 2 ? in2 : in3;
    bf16* out       = blockIdx.z == 0 ? o0  : blockIdx.z == 1 ? o1  : blockIdx.z == 2 ? o2  : o3;
    int r0 = blockIdx.y * 64, c0 = blockIdx.x * 64;
    int tx = threadIdx.x, ty = threadIdx.y;
#pragma unroll
    for (int i = ty; i < 64; i += 4)
        tile[i][tx] = in[(size_t)(r0 + i) * C + (c0 + tx)];
    __syncthreads();
#pragma unroll
    for (int i = ty; i < 64; i += 4)
        out[(size_t)(c0 + i) * R + (r0 + tx)] = (bf16)tile[tx][i];
}

// ---------------- RMSNorm: fp32 in -> bf16 out ----------------
__global__ void k_rmsnorm(const float* __restrict__ x, const float* __restrict__ w,
                          bf16* __restrict__ out) {
    int row = blockIdx.x;
    int tid = threadIdx.x;
    const float4* xr = (const float4*)(x + (size_t)row * DIM);
    float4 a = xr[tid];
    float4 b = xr[tid + 256];
    float ss = a.x*a.x + a.y*a.y + a.z*a.z + a.w*a.w
             + b.x*b.x + b.y*b.y + b.z*b.z + b.w*b.w;
#pragma unroll
    for (int off = 32; off > 0; off >>= 1) ss += __shfl_down(ss, off, 64);
    __shared__ float red[4];
    if ((tid & 63) == 0) red[tid >> 6] = ss;
    __syncthreads();
    float tot = red[0] + red[1] + red[2] + red[3];
    float inv = rsqrtf(tot * (1.0f / DIM) + EPS);
    const float4* wr = (const float4*)w;
    float4 w0 = wr[tid], w1 = wr[tid + 256];
    bf16x4* o = (bf16x4*)(out + (size_t)row * DIM);
    bf16x4 v0, v1;
    v0[0] = (bf16)(a.x * inv * w0.x); v0[1] = (bf16)(a.y * inv * w0.y);
    v0[2] = (bf16)(a.z * inv * w0.z); v0[3] = (bf16)(a.w * inv * w0.w);
    v1[0] = (bf16)(b.x * inv * w1.x); v1[1] = (bf16)(b.y * inv * w1.y);
    v1[2] = (bf16)(b.z * inv * w1.z); v1[3] = (bf16)(b.w * inv * w1.w);
    o[tid] = v0;
    o[tid + 256] = v1;
}

// =====================================================================================
// 2-barrier counted-vmcnt 256-row GEMM (C = A[M][K] @ B^T[N][K], bf16, fp32 accum).
// Per K-tile: [24 ds_read -> 64 MFMA (compiler-interleaved lgkmcnt)] | s_barrier |
//             [stage K-tile T+2 via global_load_lds, XOR-swizzled src] | vmcnt(L) |
//             s_barrier.  LDS: 2 slots x NH half-tiles (16KB each), 2-tile prefetch,
//             vmcnt never 0 in steady state. 8 waves, 1 block/CU.
// CFG 0: BN=256, 2x4 waves, single-B  (MODE 1: fused QKV + RoPE)
// CFG 1: BN=128, 4x2 waves, dual-B    (MODE 3: silu(A@B1^T) * (A@B2^T))
// CFG 2: BN=128, 4x2 waves, single-B  (MODE 2: fp32 out + residual add)
// =====================================================================================
template<int CFG, int MODE>
__global__ __launch_bounds__(512, 2) void k2b(
    const bf16* __restrict__ A, const bf16* __restrict__ B1,
    const bf16* __restrict__ B2, const float* __restrict__ resid,
    const float* __restrict__ fcos, const float* __restrict__ fsin,
    bf16* __restrict__ oq, bf16* __restrict__ ok, bf16* __restrict__ ov,
    float* __restrict__ of, int N, int K)
{
    constexpr int  BN   = (CFG == 0) ? 256 : 128;
    constexpr int  WN   = (CFG == 0) ? 4 : 2;      // waves along N
    constexpr int  WM   = 8 / WN;                  // waves along M
    constexpr int  MFR  = (256 / WM) / 16;         // m-frags per wave: 8 / 4
    constexpr bool DUAL = (CFG == 1);
    constexpr int  NH   = (CFG == 2) ? 3 : 4;      // half-tiles per K-tile
    constexpr uint32_t SLOT = (uint32_t)NH * 16384u;

    __shared__ __align__(16) char lds[2 * NH * 16384];

    const int tid  = threadIdx.x;
    const int wid  = tid >> 6;
    const int lane = tid & 63;
    const int quad = lane >> 4;
    const int l16  = lane & 15;
    const int wm   = wid / WN;
    const int wn   = wid % WN;
    const int m0   = blockIdx.y * 256;
    const int n0   = blockIdx.x * BN;
    const int NT   = K >> 6;

    // swizzled 16B-slot offsets (k-slot ^ row%8); row%8 == l16%8 for all frag rows
    const uint32_t swz0 = (uint32_t)((quad ^ (l16 & 7)) << 4);        // ks=0
    const uint32_t swz1 = (uint32_t)(((4 + quad) ^ (l16 & 7)) << 4);  // ks=1
    const uint32_t a_base  = (uint32_t)((wm * (256 / WM) + l16) * 128);
    const uint32_t b_base  = 32768u + (uint32_t)((wn * 64 + l16) * 128);

    // stage one 16KB half-tile [128 rows][64 k] of K-tile Tt into LDS.
    // H: 0/1 = A rows 0-127 / 128-255;  2(,3) = B rows per CFG.
    // global_load_lds dest is linear (wave base + lane*16); the source k-slot is
    // pre-swizzled with the same XOR the ds_read side applies (involution).
    auto stage = [&](int H, int Tt) {
        const uint32_t lb = (uint32_t)(Tt & 1) * SLOT + (uint32_t)H * 16384u
                          + (uint32_t)wid * 1024u;
        const int k0 = Tt << 6;
        const bf16* gb; int grow;
        if (H < 2) { gb = A; grow = m0 + H * 128; }
        else if constexpr (CFG == 0) { gb = B1; grow = n0 + (H - 2) * 128; }
        else if constexpr (CFG == 1) { gb = (H == 2) ? B1 : B2; grow = n0; }
        else { gb = B1; grow = n0; }
#pragma unroll
        for (int rho = 0; rho < 2; ++rho) {
            const int r  = (tid >> 3) + rho * 64;
            const int sp = (tid & 7) ^ (r & 7);
            const bf16* g = gb + (size_t)(grow + r) * K + k0 + sp * 8;
            __builtin_amdgcn_global_load_lds((gvoid_t*)g,
                (lvoid_t*)&lds[lb + (uint32_t)rho * 8192u], 16, 0, 0);
        }
    };

    f32x4 acc1[MFR][4] = {};
    f32x4 acc2[DUAL ? MFR : 1][4] = {};

    // ---------------- prologue: stage tiles 0 and 1, wait tile 0 ----------------
#pragma unroll
    for (int h = 0; h < NH; ++h) stage(h, 0);
#pragma unroll
    for (int h = 0; h < NH; ++h) stage(h, 1);
    if constexpr (NH == 4) asm volatile("s_waitcnt vmcnt(8)" ::: "memory");
    else                   asm volatile("s_waitcnt vmcnt(6)" ::: "memory");
    __builtin_amdgcn_s_barrier();

    for (int T = 0; T < NT; ++T) {
        const uint32_t sb = (uint32_t)(T & 1) * SLOT;

        // -------- read + MFMA, ks-split; compiler interleaves lgkmcnt waits --------
#pragma unroll
        for (int ks = 0; ks < 2; ++ks) {
            const uint32_t sw = ks ? swz1 : swz0;
            bf16x8 af[MFR], bf1[4], bf2[DUAL ? 4 : 1];
#pragma unroll
            for (int mi = 0; mi < MFR; ++mi)
                af[mi] = *(const bf16x8*)&lds[sb + a_base + (uint32_t)mi * 2048u + sw];
#pragma unroll
            for (int ni = 0; ni < 4; ++ni)
                bf1[ni] = *(const bf16x8*)&lds[sb + b_base + (uint32_t)ni * 2048u + sw];
            if constexpr (DUAL)
#pragma unroll
                for (int ni = 0; ni < 4; ++ni)
                    bf2[ni] = *(const bf16x8*)&lds[sb + b_base + 16384u
                                                   + (uint32_t)ni * 2048u + sw];
            __builtin_amdgcn_s_setprio(1);
#pragma unroll
            for (int mi = 0; mi < MFR; ++mi)
#pragma unroll
                for (int ni = 0; ni < 4; ++ni) {
                    acc1[mi][ni] = __builtin_amdgcn_mfma_f32_16x16x32_bf16(
                        af[mi], bf1[ni], acc1[mi][ni], 0, 0, 0);
                    if constexpr (DUAL)
                        acc2[mi][ni] = __builtin_amdgcn_mfma_f32_16x16x32_bf16(
                            af[mi], bf2[ni], acc2[mi][ni], 0, 0, 0);
                }
            __builtin_amdgcn_s_setprio(0);
        }

        // barrier 1: all waves' reads of slot sb are retired -> safe to overwrite
        __builtin_amdgcn_s_barrier();

        if (T + 2 < NT) {
#pragma unroll
            for (int h = 0; h < NH; ++h) stage(h, T + 2);   // into sb
        }
        if (T + 1 < NT) {
            if (T + 2 < NT) {   // counted gate: tile T+1 landed, T+2's stay in flight
                if constexpr (NH == 4) asm volatile("s_waitcnt vmcnt(8)" ::: "memory");
                else                   asm volatile("s_waitcnt vmcnt(6)" ::: "memory");
            } else {
                asm volatile("s_waitcnt vmcnt(0)" ::: "memory");
            }
        }
        // barrier 2: cross-wave visibility of tile T+1's staged data
        __builtin_amdgcn_s_barrier();
    }

    // -------- epilogue --------
    if constexpr (MODE == 1) {
        // block's 256 cols live in exactly one of q/k/v (2048 each)
        const int region = n0 >> 11;
        bf16* dst = region == 0 ? oq : (region == 1 ? ok : ov);
        const int c0 = (n0 & 2047) + wn * 64;
#pragma unroll
        for (int mi = 0; mi < MFR; ++mi)
#pragma unroll
            for (int i = 0; i < 4; ++i) {
                int row = m0 + wm * 128 + mi * 16 + quad * 4 + i;
                int pos = row & (SEQ - 1);
#pragma unroll
                for (int ni = 0; ni < 4; ++ni) {
                    int c = c0 + ni * 16 + l16;
                    float vA = acc1[mi][ni][i];
                    if (region < 2) {   // RoPE on q,k
                        float vB = __shfl_xor(vA, 1, 64);
                        int fi = (c & 127) >> 1;
                        float cs = fcos[pos * 64 + fi], sn = fsin[pos * 64 + fi];
                        vA = (l16 & 1) ? (vB * sn + vA * cs) : (vA * cs - vB * sn);
                    }
                    dst[(size_t)row * DIM + c] = (bf16)vA;
                }
            }
    } else if constexpr (MODE == 3) {   // silu(A@B1^T) * (A@B2^T), bf16 out
#pragma unroll
        for (int mi = 0; mi < MFR; ++mi)
#pragma unroll
            for (int i = 0; i < 4; ++i) {
                int row = m0 + wm * 64 + mi * 16 + quad * 4 + i;
#pragma unroll
                for (int ni = 0; ni < 4; ++ni) {
                    int col = n0 + wn * 64 + ni * 16 + l16;
                    float v1 = acc1[mi][ni][i];
                    float v2 = acc2[mi][ni][i];
                    float g = v1 / (1.0f + __expf(-v1));
                    oq[(size_t)row * (size_t)N + col] = (bf16)(g * v2);
                }
            }
    } else {   // MODE 2: fp32 out = resid + A@B1^T
#pragma unroll
        for (int mi = 0; mi < MFR; ++mi)
#pragma unroll
            for (int i = 0; i < 4; ++i) {
                int row = m0 + wm * 64 + mi * 16 + quad * 4 + i;
#pragma unroll
                for (int ni = 0; ni < 4; ++ni) {
                    int col = n0 + wn * 64 + ni * 16 + l16;
                    of[(size_t)row * N + col] = resid[(size_t)row * N + col]
                                              + acc1[mi][ni][i];
                }
            }
    }
}

// ---------------- Flash attention (causal), per (qtile, batch*head) -----------------
__global__ __launch_bounds__(256, 2) void k_flash(
    const bf16* __restrict__ q, const bf16* __restrict__ k,
    const bf16* __restrict__ v, bf16* __restrict__ o)
{
    const int qt = 15 - blockIdx.x;    // longest blocks first
    const int bh = blockIdx.y;
    const int b  = bh >> 4, h = bh & 15;
    const int tid  = threadIdx.x;
    const int wid  = tid >> 6, lane = tid & 63;
    const int quad = lane >> 4, l16 = lane & 15;

    __shared__ bf16 Ks [128][136];   // K tile [key][d]; reused as P tile [q][key]
    __shared__ bf16 Vts[128][136];   // V^T tile [d][key]

    const int q0 = qt * 128;
    const size_t baseQ  = ((size_t)b * SEQ + q0) * DIM + (size_t)h * HD;
    const size_t baseKV = ((size_t)b * SEQ) * DIM + (size_t)h * HD;

    bf16x8 qf[2][4];
#pragma unroll
    for (int mi = 0; mi < 2; ++mi)
#pragma unroll
        for (int ks = 0; ks < 4; ++ks)
            qf[mi][ks] = *(const bf16x8*)&q[baseQ +
                (size_t)(wid * 32 + mi * 16 + l16) * DIM + ks * 32 + quad * 8];

    f32x4 acc_o[2][8] = {};
    float m_run[2][4], l_run[2][4];
#pragma unroll
    for (int mi = 0; mi < 2; ++mi)
#pragma unroll
        for (int i = 0; i < 4; ++i) { m_run[mi][i] = -INFINITY; l_run[mi][i] = 0.f; }

    const float scale = 0.08838834764831845f;   // 1/sqrt(128)
    const int krow = tid >> 1, kcol = (tid & 1) * 64;

    for (int kt = 0; kt <= qt; ++kt) {
        const int kbase = kt * 128;
        __syncthreads();
#pragma unroll
        for (int j = 0; j < 8; ++j)
            *(uint4*)&Ks[krow][kcol + j * 8] =
                *(const uint4*)&k[baseKV + (size_t)(kbase + krow) * DIM + kcol + j * 8];
#pragma unroll
        for (int j = 0; j < 8; ++j) {
            bf16x8 vv = *(const bf16x8*)&v[baseKV + (size_t)(kbase + krow) * DIM + kcol + j * 8];
#pragma unroll
            for (int e = 0; e < 8; ++e)
                Vts[kcol + j * 8 + e][krow] = vv[e];
        }
        __syncthreads();

        f32x4 accs[2][8] = {};
#pragma unroll
        for (int ks = 0; ks < 4; ++ks)
#pragma unroll
            for (int ni = 0; ni < 8; ++ni) {
                bf16x8 kf = *(const bf16x8*)&Ks[ni * 16 + l16][ks * 32 + quad * 8];
#pragma unroll
                for (int mi = 0; mi < 2; ++mi)
                    accs[mi][ni] = __builtin_amdgcn_mfma_f32_16x16x32_bf16(
                        qf[mi][ks], kf, accs[mi][ni], 0, 0, 0);
            }

#pragma unroll
        for (int mi = 0; mi < 2; ++mi)
#pragma unroll
            for (int i = 0; i < 4; ++i) {
                int grow = q0 + wid * 32 + mi * 16 + quad * 4 + i;
                float mx = -INFINITY;
#pragma unroll
                for (int ni = 0; ni < 8; ++ni) {
                    float sv = accs[mi][ni][i] * scale;
                    int col = kbase + ni * 16 + l16;
                    if (col > grow) sv = -INFINITY;
                    accs[mi][ni][i] = sv;
                    mx = fmaxf(mx, sv);
                }
                mx = fmaxf(mx, __shfl_xor(mx, 1, 64));
                mx = fmaxf(mx, __shfl_xor(mx, 2, 64));
                mx = fmaxf(mx, __shfl_xor(mx, 4, 64));
                mx = fmaxf(mx, __shfl_xor(mx, 8, 64));
                float mnew  = fmaxf(m_run[mi][i], mx);
                float alpha = __expf(m_run[mi][i] - mnew);
                m_run[mi][i] = mnew;
                float rsum = 0.f;
#pragma unroll
                for (int ni = 0; ni < 8; ++ni) {
                    float p = __expf(accs[mi][ni][i] - mnew);
                    accs[mi][ni][i] = p;
                    rsum += p;
                }
                rsum += __shfl_xor(rsum, 1, 64);
                rsum += __shfl_xor(rsum, 2, 64);
                rsum += __shfl_xor(rsum, 4, 64);
                rsum += __shfl_xor(rsum, 8, 64);
                l_run[mi][i] = l_run[mi][i] * alpha + rsum;
#pragma unroll
                for (int ni = 0; ni < 8; ++ni) acc_o[mi][ni][i] *= alpha;
            }

        __syncthreads();
#pragma unroll
        for (int mi = 0; mi < 2; ++mi)
#pragma unroll
            for (int ni = 0; ni < 8; ++ni)
#pragma unroll
                for (int i = 0; i < 4; ++i)
                    Ks[wid * 32 + mi * 16 + quad * 4 + i][ni * 16 + l16] =
                        (bf16)accs[mi][ni][i];
        __syncthreads();

#pragma unroll
        for (int ks2 = 0; ks2 < 4; ++ks2) {
            bf16x8 pf[2];
#pragma unroll
            for (int mi = 0; mi < 2; ++mi)
                pf[mi] = *(const bf16x8*)&Ks[wid * 32 + mi * 16 + l16][ks2 * 32 + quad * 8];
#pragma unroll
            for (int ni = 0; ni < 8; ++ni) {
                bf16x8 vf = *(const bf16x8*)&Vts[ni * 16 + l16][ks2 * 32 + quad * 8];
#pragma unroll
                for (int mi = 0; mi < 2; ++mi)
                    acc_o[mi][ni] = __builtin_amdgcn_mfma_f32_16x16x32_bf16(
                        pf[mi], vf, acc_o[mi][ni], 0, 0, 0);
            }
        }
    }

#pragma unroll
    for (int mi = 0; mi < 2; ++mi)
#pragma unroll
        for (int i = 0; i < 4; ++i) {
            float invl = 1.0f / l_run[mi][i];
            int row = q0 + wid * 32 + mi * 16 + quad * 4 + i;
            size_t rb = ((size_t)b * SEQ + row) * DIM + (size_t)h * HD;
#pragma unroll
            for (int ni = 0; ni < 8; ++ni)
                o[rb + ni * 16 + l16] = (bf16)(acc_o[mi][ni][i] * invl);
        }
}

// ------------------------------- host launcher ---------------------------------------
extern "C" void kernel_launch(void* const* d_in, const int* in_sizes, int n_in,
                              void* d_out, int out_size, void* d_ws, size_t ws_size,
                              hipStream_t stream)
{
    (void)in_sizes; (void)n_in; (void)out_size; (void)ws_size;
    const float* x    = (const float*)d_in[0];
    const float* fcos = (const float*)d_in[1];
    const float* fsin = (const float*)d_in[2];
    const float* wq   = (const float*)d_in[4];
    const float* wk   = (const float*)d_in[5];
    const float* wv   = (const float*)d_in[6];
    const float* wo   = (const float*)d_in[7];
    const float* w1   = (const float*)d_in[8];
    const float* w2   = (const float*)d_in[9];
    const float* w3   = (const float*)d_in[10];
    const float* anw  = (const float*)d_in[11];
    const float* fnw  = (const float*)d_in[12];
    float* out = (float*)d_out;

    char* ws = (char*)d_ws;
    size_t off = 0;
    auto alloc = [&](size_t bytes) { void* p = ws + off; off += (bytes + 255) & ~255ull; return p; };
    bf16* wqT = (bf16*)alloc((size_t)DIM * DIM * 2);    // wq/wk/wv contiguous -> one B matrix
    bf16* wkT = (bf16*)alloc((size_t)DIM * DIM * 2);
    bf16* wvT = (bf16*)alloc((size_t)DIM * DIM * 2);
    bf16* woT = (bf16*)alloc((size_t)DIM * DIM * 2);
    bf16* w1T = (bf16*)alloc((size_t)HIDDEN * DIM * 2);
    bf16* w3T = (bf16*)alloc((size_t)HIDDEN * DIM * 2);
    bf16* xn  = (bf16*)alloc((size_t)MTOK * DIM * 2);   // also hn
    bf16* qb  = (bf16*)alloc((size_t)MTOK * DIM * 2);   // also attn out
    bf16* kb  = (bf16*)alloc((size_t)MTOK * DIM * 2);
    bf16* vb  = (bf16*)alloc((size_t)MTOK * DIM * 2);
    bf16* ffb = (bf16*)alloc((size_t)MTOK * HIDDEN * 2);
    bf16* w2T = kb;   // w2T [DIM][HIDDEN] reuses k+v region after attention

    dim3 tb(64, 4);
    // all four DIM x DIM weight transposes in ONE dispatch
    k_transpose4<<<dim3(DIM / 64, DIM / 64, 4), tb, 0, stream>>>(
        wq, wk, wv, wo, wqT, wkT, wvT, woT, DIM, DIM);
    // w1 + w3 in one dispatch
    k_transpose4<<<dim3(HIDDEN / 64, DIM / 64, 2), tb, 0, stream>>>(
        w1, w3, nullptr, nullptr, w1T, w3T, nullptr, nullptr, DIM, HIDDEN);

    k_rmsnorm<<<MTOK, 256, 0, stream>>>(x, anw, xn);

    // fused QKV projection + RoPE (B = [wqT|wkT|wvT] contiguous, N=6144)
    k2b<0, 1><<<dim3(3 * DIM / 256, MTOK / 256), 512, 0, stream>>>(
        xn, wqT, nullptr, nullptr, fcos, fsin, qb, kb, vb, nullptr, 3 * DIM, DIM);

    // attention -> writes into qb
    k_flash<<<dim3(SEQ / 128, 2 * NHEADS), 256, 0, stream>>>(qb, kb, vb, qb);

    // w2 transpose into dead k/v region (after flash; aliases kb)
    k_transpose4<<<dim3(DIM / 64, HIDDEN / 64, 1), tb, 0, stream>>>(
        w2, nullptr, nullptr, nullptr, w2T, nullptr, nullptr, nullptr, HIDDEN, DIM);

    // h = x + attn @ wo   (fp32, into d_out)
    k2b<2, 2><<<dim3(DIM / 128, MTOK / 256), 512, 0, stream>>>(
        qb, woT, nullptr, x, nullptr, nullptr, nullptr, nullptr, nullptr, out, DIM, DIM);

    k_rmsnorm<<<MTOK, 256, 0, stream>>>(out, fnw, xn);

    // ff = silu(hn@w1) * (hn@w3)  -- dual-B, BN=128
    k2b<1, 3><<<dim3(HIDDEN / 128, MTOK / 256), 512, 0, stream>>>(
        xn, w1T, w3T, nullptr, nullptr, nullptr, ffb, nullptr, nullptr, nullptr,
        HIDDEN, DIM);

    // out = h + ff @ w2
    k2b<2, 2><<<dim3(DIM / 128, MTOK / 256), 512, 0, stream>>>(
        ffb, w2T, nullptr, out, nullptr, nullptr, nullptr, nullptr, nullptr, out,
        DIM, HIDDEN);
}

// Round 3
// 1057.436 us; speedup vs baseline: 1.1205x; 1.0217x over previous
//
#include <hip/hip_runtime.h>
#include <cmath>

#define DIM    2048
#define NHEADS 16
#define HD     128
#define HIDDEN 8192
#define SEQ    2048
#define MTOK   4096   // BATCH*SEQ
#define EPS    1e-6f

typedef __bf16 bf16;
typedef __bf16 bf16x8 __attribute__((ext_vector_type(8)));
typedef __bf16 bf16x4 __attribute__((ext_vector_type(4)));
typedef float  f32x4  __attribute__((ext_vector_type(4)));

typedef __attribute__((address_space(1))) const void gvoid_t;
typedef __attribute__((address_space(3))) void lvoid_t;

// ------- batched transpose + fp32->bf16 convert: out[c][r] = in[r][c], z picks matrix ----
__global__ void k_transpose4(const float* __restrict__ in0, const float* __restrict__ in1,
                             const float* __restrict__ in2, const float* __restrict__ in3,
                             bf16* __restrict__ o0, bf16* __restrict__ o1,
                             bf16* __restrict__ o2, bf16* __restrict__ o3,
                             int R, int C) {
    __shared__ float tile[64][65];
    const float* in = blockIdx.z == 0 ? in0 : blockIdx.z == 1 ? in1 : blockIdx.z == 2 ? in2 : in3;
    bf16* out       = blockIdx.z == 0 ? o0  : blockIdx.z == 1 ? o1  : blockIdx.z == 2 ? o2  : o3;
    int r0 = blockIdx.y * 64, c0 = blockIdx.x * 64;
    int tx = threadIdx.x, ty = threadIdx.y;
#pragma unroll
    for (int i = ty; i < 64; i += 4)
        tile[i][tx] = in[(size_t)(r0 + i) * C + (c0 + tx)];
    __syncthreads();
#pragma unroll
    for (int i = ty; i < 64; i += 4)
        out[(size_t)(c0 + i) * R + (r0 + tx)] = (bf16)tile[tx][i];
}

// ------- per-(b,h) transpose of V: v[(b*SEQ+s)][h*HD+d] -> vT[((b*16+h)*HD+d)*SEQ+s] ----
__global__ void k_transposeV(const bf16* __restrict__ v, bf16* __restrict__ vT) {
    __shared__ bf16 t[64][66];
    const int bh = blockIdx.z;
    const int b  = bh >> 4, h = bh & 15;
    const int s0 = blockIdx.x * 64, d0 = blockIdx.y * 64;
    const int tx = threadIdx.x, ty = threadIdx.y;
#pragma unroll
    for (int i = ty; i < 64; i += 4)
        t[i][tx] = v[((size_t)(b * SEQ + s0 + i)) * DIM + h * HD + d0 + tx];
    __syncthreads();
#pragma unroll
    for (int i = ty; i < 64; i += 4)
        vT[((size_t)(bh * HD + d0 + i)) * SEQ + s0 + tx] = t[tx][i];
}

// ---------------- RMSNorm: fp32 in -> bf16 out ----------------
__global__ void k_rmsnorm(const float* __restrict__ x, const float* __restrict__ w,
                          bf16* __restrict__ out) {
    int row = blockIdx.x;
    int tid = threadIdx.x;
    const float4* xr = (const float4*)(x + (size_t)row * DIM);
    float4 a = xr[tid];
    float4 b = xr[tid + 256];
    float ss = a.x*a.x + a.y*a.y + a.z*a.z + a.w*a.w
             + b.x*b.x + b.y*b.y + b.z*b.z + b.w*b.w;
#pragma unroll
    for (int off = 32; off > 0; off >>= 1) ss += __shfl_down(ss, off, 64);
    __shared__ float red[4];
    if ((tid & 63) == 0) red[tid >> 6] = ss;
    __syncthreads();
    float tot = red[0] + red[1] + red[2] + red[3];
    float inv = rsqrtf(tot * (1.0f / DIM) + EPS);
    const float4* wr = (const float4*)w;
    float4 w0 = wr[tid], w1 = wr[tid + 256];
    bf16x4* o = (bf16x4*)(out + (size_t)row * DIM);
    bf16x4 v0, v1;
    v0[0] = (bf16)(a.x * inv * w0.x); v0[1] = (bf16)(a.y * inv * w0.y);
    v0[2] = (bf16)(a.z * inv * w0.z); v0[3] = (bf16)(a.w * inv * w0.w);
    v1[0] = (bf16)(b.x * inv * w1.x); v1[1] = (bf16)(b.y * inv * w1.y);
    v1[2] = (bf16)(b.z * inv * w1.z); v1[3] = (bf16)(b.w * inv * w1.w);
    o[tid] = v0;
    o[tid + 256] = v1;
}

// =====================================================================================
// 2-barrier counted-vmcnt 256x128 GEMM (C = A[M][K] @ B^T[N][K], bf16, fp32 accum).
// Uniform geometry: BM=256, BN=128, 8 waves as 4x2, per-wave 64x64 per output matrix.
// Per K-tile: [reads -> MFMA (compiler-interleaved lgkmcnt)] | s_barrier |
//             [stage K-tile T+2 via global_load_lds, XOR-swizzled src] | vmcnt(L) |
//             s_barrier.  2-tile prefetch, vmcnt never 0 in steady state. 1 block/CU.
// DUALB=1 adds B2 tile + second accumulator (MODE 3).
// MODE 1: fused QKV + RoPE epilogue.  MODE 2: fp32 out + residual.  MODE 3: silu*mul.
// =====================================================================================
template<int DUALB, int MODE>
__global__ __launch_bounds__(512, 2) void k2b(
    const bf16* __restrict__ A, const bf16* __restrict__ B1,
    const bf16* __restrict__ B2, const float* __restrict__ resid,
    const float* __restrict__ fcos, const float* __restrict__ fsin,
    bf16* __restrict__ oq, bf16* __restrict__ ok, bf16* __restrict__ ov,
    float* __restrict__ of, int N, int K)
{
    constexpr int  MFR  = 4;                       // m-frags per wave
    constexpr int  NH   = DUALB ? 4 : 3;           // half-tiles per K-tile
    constexpr uint32_t SLOT = (uint32_t)NH * 16384u;

    __shared__ __align__(16) char lds[2 * NH * 16384];

    const int tid  = threadIdx.x;
    const int wid  = tid >> 6;
    const int lane = tid & 63;
    const int quad = lane >> 4;
    const int l16  = lane & 15;
    const int wm   = wid >> 1;
    const int wn   = wid & 1;
    const int m0   = blockIdx.y * 256;
    const int n0   = blockIdx.x * 128;
    const int NT   = K >> 6;

    // swizzled 16B-slot offsets (k-slot ^ row%8); row%8 == l16%8 for all frag rows
    const uint32_t swz0 = (uint32_t)((quad ^ (l16 & 7)) << 4);        // ks=0
    const uint32_t swz1 = (uint32_t)(((4 + quad) ^ (l16 & 7)) << 4);  // ks=1
    const uint32_t a_base = (uint32_t)((wm * 64 + l16) * 128);
    const uint32_t b_base = 32768u + (uint32_t)((wn * 64 + l16) * 128);

    // stage one 16KB half-tile [128 rows][64 k] of K-tile Tt into LDS.
    // H: 0/1 = A rows 0-127 / 128-255;  2 = B1;  3 = B2.
    // global_load_lds dest is linear (wave base + lane*16); the source k-slot is
    // pre-swizzled with the same XOR the ds_read side applies (involution).
    auto stage = [&](int H, int Tt) {
        const uint32_t lb = (uint32_t)(Tt & 1) * SLOT + (uint32_t)H * 16384u
                          + (uint32_t)wid * 1024u;
        const int k0 = Tt << 6;
        const bf16* gb; int grow;
        if (H < 2) { gb = A; grow = m0 + H * 128; }
        else if (H == 2) { gb = B1; grow = n0; }
        else { gb = B2; grow = n0; }
#pragma unroll
        for (int rho = 0; rho < 2; ++rho) {
            const int r  = (tid >> 3) + rho * 64;
            const int sp = (tid & 7) ^ (r & 7);
            const bf16* g = gb + (size_t)(grow + r) * K + k0 + sp * 8;
            __builtin_amdgcn_global_load_lds((gvoid_t*)g,
                (lvoid_t*)&lds[lb + (uint32_t)rho * 8192u], 16, 0, 0);
        }
    };

    f32x4 acc1[MFR][4] = {};
    f32x4 acc2[DUALB ? MFR : 1][4] = {};

    // ---------------- prologue: stage tiles 0 and 1, wait tile 0 ----------------
#pragma unroll
    for (int h = 0; h < NH; ++h) stage(h, 0);
#pragma unroll
    for (int h = 0; h < NH; ++h) stage(h, 1);
    if constexpr (NH == 4) asm volatile("s_waitcnt vmcnt(8)" ::: "memory");
    else                   asm volatile("s_waitcnt vmcnt(6)" ::: "memory");
    __builtin_amdgcn_s_barrier();

    for (int T = 0; T < NT; ++T) {
        const uint32_t sb = (uint32_t)(T & 1) * SLOT;

        // -------- read + MFMA, ks-split; compiler interleaves lgkmcnt waits --------
#pragma unroll
        for (int ks = 0; ks < 2; ++ks) {
            const uint32_t sw = ks ? swz1 : swz0;
            bf16x8 af[MFR], bf1[4], bf2[DUALB ? 4 : 1];
#pragma unroll
            for (int mi = 0; mi < MFR; ++mi)
                af[mi] = *(const bf16x8*)&lds[sb + a_base + (uint32_t)mi * 2048u + sw];
#pragma unroll
            for (int ni = 0; ni < 4; ++ni)
                bf1[ni] = *(const bf16x8*)&lds[sb + b_base + (uint32_t)ni * 2048u + sw];
            if constexpr (DUALB)
#pragma unroll
                for (int ni = 0; ni < 4; ++ni)
                    bf2[ni] = *(const bf16x8*)&lds[sb + b_base + 16384u
                                                   + (uint32_t)ni * 2048u + sw];
            __builtin_amdgcn_s_setprio(1);
#pragma unroll
            for (int mi = 0; mi < MFR; ++mi)
#pragma unroll
                for (int ni = 0; ni < 4; ++ni) {
                    acc1[mi][ni] = __builtin_amdgcn_mfma_f32_16x16x32_bf16(
                        af[mi], bf1[ni], acc1[mi][ni], 0, 0, 0);
                    if constexpr (DUALB)
                        acc2[mi][ni] = __builtin_amdgcn_mfma_f32_16x16x32_bf16(
                            af[mi], bf2[ni], acc2[mi][ni], 0, 0, 0);
                }
            __builtin_amdgcn_s_setprio(0);
        }

        // barrier 1: all waves' reads of slot sb are retired -> safe to overwrite
        __builtin_amdgcn_s_barrier();

        if (T + 2 < NT) {
#pragma unroll
            for (int h = 0; h < NH; ++h) stage(h, T + 2);   // into sb
        }
        if (T + 1 < NT) {
            if (T + 2 < NT) {   // counted gate: tile T+1 landed, T+2's stay in flight
                if constexpr (NH == 4) asm volatile("s_waitcnt vmcnt(8)" ::: "memory");
                else                   asm volatile("s_waitcnt vmcnt(6)" ::: "memory");
            } else {
                asm volatile("s_waitcnt vmcnt(0)" ::: "memory");
            }
        }
        // barrier 2: cross-wave visibility of tile T+1's staged data
        __builtin_amdgcn_s_barrier();
    }

    // -------- epilogue --------
    if constexpr (MODE == 1) {
        // block's 128 cols live in exactly one of q/k/v (2048 each)
        const int region = n0 >> 11;
        bf16* dst = region == 0 ? oq : (region == 1 ? ok : ov);
        const int c0 = (n0 & 2047) + wn * 64;
#pragma unroll
        for (int mi = 0; mi < MFR; ++mi)
#pragma unroll
            for (int i = 0; i < 4; ++i) {
                int row = m0 + wm * 64 + mi * 16 + quad * 4 + i;
                int pos = row & (SEQ - 1);
#pragma unroll
                for (int ni = 0; ni < 4; ++ni) {
                    int c = c0 + ni * 16 + l16;
                    float vA = acc1[mi][ni][i];
                    if (region < 2) {   // RoPE on q,k
                        float vB = __shfl_xor(vA, 1, 64);
                        int fi = (c & 127) >> 1;
                        float cs = fcos[pos * 64 + fi], sn = fsin[pos * 64 + fi];
                        vA = (l16 & 1) ? (vB * sn + vA * cs) : (vA * cs - vB * sn);
                    }
                    dst[(size_t)row * DIM + c] = (bf16)vA;
                }
            }
    } else if constexpr (MODE == 3) {   // silu(A@B1^T) * (A@B2^T), bf16 out
#pragma unroll
        for (int mi = 0; mi < MFR; ++mi)
#pragma unroll
            for (int i = 0; i < 4; ++i) {
                int row = m0 + wm * 64 + mi * 16 + quad * 4 + i;
#pragma unroll
                for (int ni = 0; ni < 4; ++ni) {
                    int col = n0 + wn * 64 + ni * 16 + l16;
                    float v1 = acc1[mi][ni][i];
                    float v2 = acc2[mi][ni][i];
                    float g = v1 / (1.0f + __expf(-v1));
                    oq[(size_t)row * (size_t)N + col] = (bf16)(g * v2);
                }
            }
    } else {   // MODE 2: fp32 out = resid + A@B1^T
#pragma unroll
        for (int mi = 0; mi < MFR; ++mi)
#pragma unroll
            for (int i = 0; i < 4; ++i) {
                int row = m0 + wm * 64 + mi * 16 + quad * 4 + i;
#pragma unroll
                for (int ni = 0; ni < 4; ++ni) {
                    int col = n0 + wn * 64 + ni * 16 + l16;
                    of[(size_t)row * N + col] = resid[(size_t)row * N + col]
                                              + acc1[mi][ni][i];
                }
            }
    }
}

// ---------------- Flash attention (causal), per (qtile, batch*head) -----------------
// vT is the pre-transposed V: vT[((b*16+h)*HD + d)*SEQ + s]  (coalesced V^T loads)
__global__ __launch_bounds__(256, 2) void k_flash(
    const bf16* __restrict__ q, const bf16* __restrict__ k,
    const bf16* __restrict__ vT, bf16* __restrict__ o)
{
    const int qt = 15 - blockIdx.x;    // longest blocks first
    const int bh = blockIdx.y;
    const int b  = bh >> 4, h = bh & 15;
    const int tid  = threadIdx.x;
    const int wid  = tid >> 6, lane = tid & 63;
    const int quad = lane >> 4, l16 = lane & 15;

    __shared__ bf16 Ks [128][136];   // K tile [key][d]; reused as P tile [q][key]
    __shared__ bf16 Vts[128][136];   // V^T tile [d][key]

    const int q0 = qt * 128;
    const size_t baseQ  = ((size_t)b * SEQ + q0) * DIM + (size_t)h * HD;
    const size_t baseKV = ((size_t)b * SEQ) * DIM + (size_t)h * HD;
    const size_t baseVT = (size_t)bh * HD * SEQ;

    bf16x8 qf[2][4];
#pragma unroll
    for (int mi = 0; mi < 2; ++mi)
#pragma unroll
        for (int ks = 0; ks < 4; ++ks)
            qf[mi][ks] = *(const bf16x8*)&q[baseQ +
                (size_t)(wid * 32 + mi * 16 + l16) * DIM + ks * 32 + quad * 8];

    f32x4 acc_o[2][8] = {};
    float m_run[2][4], l_run[2][4];
#pragma unroll
    for (int mi = 0; mi < 2; ++mi)
#pragma unroll
        for (int i = 0; i < 4; ++i) { m_run[mi][i] = -INFINITY; l_run[mi][i] = 0.f; }

    const float scale = 0.08838834764831845f;   // 1/sqrt(128)
    const int krow = tid >> 1, kcol = (tid & 1) * 64;

    for (int kt = 0; kt <= qt; ++kt) {
        const int kbase = kt * 128;
        __syncthreads();
#pragma unroll
        for (int j = 0; j < 8; ++j)
            *(uint4*)&Ks[krow][kcol + j * 8] =
                *(const uint4*)&k[baseKV + (size_t)(kbase + krow) * DIM + kcol + j * 8];
#pragma unroll
        for (int j = 0; j < 8; ++j)
            *(uint4*)&Vts[krow][kcol + j * 8] =
                *(const uint4*)&vT[baseVT + (size_t)krow * SEQ + kbase + kcol + j * 8];
        __syncthreads();

        f32x4 accs[2][8] = {};
#pragma unroll
        for (int ks = 0; ks < 4; ++ks)
#pragma unroll
            for (int ni = 0; ni < 8; ++ni) {
                bf16x8 kf = *(const bf16x8*)&Ks[ni * 16 + l16][ks * 32 + quad * 8];
#pragma unroll
                for (int mi = 0; mi < 2; ++mi)
                    accs[mi][ni] = __builtin_amdgcn_mfma_f32_16x16x32_bf16(
                        qf[mi][ks], kf, accs[mi][ni], 0, 0, 0);
            }

#pragma unroll
        for (int mi = 0; mi < 2; ++mi)
#pragma unroll
            for (int i = 0; i < 4; ++i) {
                int grow = q0 + wid * 32 + mi * 16 + quad * 4 + i;
                float mx = -INFINITY;
#pragma unroll
                for (int ni = 0; ni < 8; ++ni) {
                    float sv = accs[mi][ni][i] * scale;
                    int col = kbase + ni * 16 + l16;
                    if (col > grow) sv = -INFINITY;
                    accs[mi][ni][i] = sv;
                    mx = fmaxf(mx, sv);
                }
                mx = fmaxf(mx, __shfl_xor(mx, 1, 64));
                mx = fmaxf(mx, __shfl_xor(mx, 2, 64));
                mx = fmaxf(mx, __shfl_xor(mx, 4, 64));
                mx = fmaxf(mx, __shfl_xor(mx, 8, 64));
                float mnew  = fmaxf(m_run[mi][i], mx);
                float alpha = __expf(m_run[mi][i] - mnew);
                m_run[mi][i] = mnew;
                float rsum = 0.f;
#pragma unroll
                for (int ni = 0; ni < 8; ++ni) {
                    float p = __expf(accs[mi][ni][i] - mnew);
                    accs[mi][ni][i] = p;
                    rsum += p;
                }
                rsum += __shfl_xor(rsum, 1, 64);
                rsum += __shfl_xor(rsum, 2, 64);
                rsum += __shfl_xor(rsum, 4, 64);
                rsum += __shfl_xor(rsum, 8, 64);
                l_run[mi][i] = l_run[mi][i] * alpha + rsum;
#pragma unroll
                for (int ni = 0; ni < 8; ++ni) acc_o[mi][ni][i] *= alpha;
            }

        __syncthreads();
#pragma unroll
        for (int mi = 0; mi < 2; ++mi)
#pragma unroll
            for (int ni = 0; ni < 8; ++ni)
#pragma unroll
                for (int i = 0; i < 4; ++i)
                    Ks[wid * 32 + mi * 16 + quad * 4 + i][ni * 16 + l16] =
                        (bf16)accs[mi][ni][i];
        __syncthreads();

#pragma unroll
        for (int ks2 = 0; ks2 < 4; ++ks2) {
            bf16x8 pf[2];
#pragma unroll
            for (int mi = 0; mi < 2; ++mi)
                pf[mi] = *(const bf16x8*)&Ks[wid * 32 + mi * 16 + l16][ks2 * 32 + quad * 8];
#pragma unroll
            for (int ni = 0; ni < 8; ++ni) {
                bf16x8 vf = *(const bf16x8*)&Vts[ni * 16 + l16][ks2 * 32 + quad * 8];
#pragma unroll
                for (int mi = 0; mi < 2; ++mi)
                    acc_o[mi][ni] = __builtin_amdgcn_mfma_f32_16x16x32_bf16(
                        pf[mi], vf, acc_o[mi][ni], 0, 0, 0);
            }
        }
    }

#pragma unroll
    for (int mi = 0; mi < 2; ++mi)
#pragma unroll
        for (int i = 0; i < 4; ++i) {
            float invl = 1.0f / l_run[mi][i];
            int row = q0 + wid * 32 + mi * 16 + quad * 4 + i;
            size_t rb = ((size_t)b * SEQ + row) * DIM + (size_t)h * HD;
#pragma unroll
            for (int ni = 0; ni < 8; ++ni)
                o[rb + ni * 16 + l16] = (bf16)(acc_o[mi][ni][i] * invl);
        }
}

// ------------------------------- host launcher ---------------------------------------
extern "C" void kernel_launch(void* const* d_in, const int* in_sizes, int n_in,
                              void* d_out, int out_size, void* d_ws, size_t ws_size,
                              hipStream_t stream)
{
    (void)in_sizes; (void)n_in; (void)out_size; (void)ws_size;
    const float* x    = (const float*)d_in[0];
    const float* fcos = (const float*)d_in[1];
    const float* fsin = (const float*)d_in[2];
    const float* wq   = (const float*)d_in[4];
    const float* wk   = (const float*)d_in[5];
    const float* wv   = (const float*)d_in[6];
    const float* wo   = (const float*)d_in[7];
    const float* w1   = (const float*)d_in[8];
    const float* w2   = (const float*)d_in[9];
    const float* w3   = (const float*)d_in[10];
    const float* anw  = (const float*)d_in[11];
    const float* fnw  = (const float*)d_in[12];
    float* out = (float*)d_out;

    char* ws = (char*)d_ws;
    size_t off = 0;
    auto alloc = [&](size_t bytes) { void* p = ws + off; off += (bytes + 255) & ~255ull; return p; };
    bf16* wqT = (bf16*)alloc((size_t)DIM * DIM * 2);    // wq/wk/wv contiguous -> one B matrix
    bf16* wkT = (bf16*)alloc((size_t)DIM * DIM * 2);
    bf16* wvT = (bf16*)alloc((size_t)DIM * DIM * 2);
    bf16* woT = (bf16*)alloc((size_t)DIM * DIM * 2);
    bf16* w1T = (bf16*)alloc((size_t)HIDDEN * DIM * 2);
    bf16* w3T = (bf16*)alloc((size_t)HIDDEN * DIM * 2);
    bf16* xn  = (bf16*)alloc((size_t)MTOK * DIM * 2);   // also hn
    bf16* qb  = (bf16*)alloc((size_t)MTOK * DIM * 2);   // also attn out
    bf16* kb  = (bf16*)alloc((size_t)MTOK * DIM * 2);
    bf16* vb  = (bf16*)alloc((size_t)MTOK * DIM * 2);
    bf16* ffb = (bf16*)alloc((size_t)MTOK * HIDDEN * 2);
    bf16* w2T = kb;   // w2T [DIM][HIDDEN] reuses k+v region after attention
    bf16* vTb = ffb;  // V^T [32][128][2048] lives in ffb until the FFN GEMM needs it

    dim3 tb(64, 4);
    // all four DIM x DIM weight transposes in ONE dispatch
    k_transpose4<<<dim3(DIM / 64, DIM / 64, 4), tb, 0, stream>>>(
        wq, wk, wv, wo, wqT, wkT, wvT, woT, DIM, DIM);
    // w1 + w3 in one dispatch
    k_transpose4<<<dim3(HIDDEN / 64, DIM / 64, 2), tb, 0, stream>>>(
        w1, w3, nullptr, nullptr, w1T, w3T, nullptr, nullptr, DIM, HIDDEN);

    k_rmsnorm<<<MTOK, 256, 0, stream>>>(x, anw, xn);

    // fused QKV projection + RoPE (B = [wqT|wkT|wvT] contiguous, N=6144)
    k2b<0, 1><<<dim3(3 * DIM / 128, MTOK / 256), 512, 0, stream>>>(
        xn, wqT, nullptr, nullptr, fcos, fsin, qb, kb, vb, nullptr, 3 * DIM, DIM);

    // V -> V^T (per b,h) for coalesced flash V loads
    k_transposeV<<<dim3(SEQ / 64, HD / 64, 2 * NHEADS), tb, 0, stream>>>(vb, vTb);

    // attention -> writes into qb
    k_flash<<<dim3(SEQ / 128, 2 * NHEADS), 256, 0, stream>>>(qb, kb, vTb, qb);

    // w2 transpose into dead k/v region (after flash; aliases kb)
    k_transpose4<<<dim3(DIM / 64, HIDDEN / 64, 1), tb, 0, stream>>>(
        w2, nullptr, nullptr, nullptr, w2T, nullptr, nullptr, nullptr, HIDDEN, DIM);

    // h = x + attn @ wo   (fp32, into d_out)
    k2b<0, 2><<<dim3(DIM / 128, MTOK / 256), 512, 0, stream>>>(
        qb, woT, nullptr, x, nullptr, nullptr, nullptr, nullptr, nullptr, out, DIM, DIM);

    k_rmsnorm<<<MTOK, 256, 0, stream>>>(out, fnw, xn);

    // ff = silu(hn@w1) * (hn@w3)  -- dual-B, BN=128 (overwrites vT region, done with it)
    k2b<1, 3><<<dim3(HIDDEN / 128, MTOK / 256), 512, 0, stream>>>(
        xn, w1T, w3T, nullptr, nullptr, nullptr, ffb, nullptr, nullptr, nullptr,
        HIDDEN, DIM);

    // out = h + ff @ w2
    k2b<0, 2><<<dim3(DIM / 128, MTOK / 256), 512, 0, stream>>>(
        ffb, w2T, nullptr, out, nullptr, nullptr, nullptr, nullptr, nullptr, out,
        DIM, HIDDEN);
}